// Round 3
// baseline (436.122 us; speedup 1.0000x reference)
//
#include <hip/hip_runtime.h>

// Problem constants (from reference): N_T=5, 32x32 grid, N=1024, batch=4.
#define NT   5
#define NY   32
#define NX   32
#define NN   1024          // N = NY*NX
#define QDIM 5120          // NT * NN
#define NB   4

// Canonical stencil offset order (matches reference's offs list):
// 0:(0,0) 1:(0,1) 2:(0,-1) 3:(1,0) 4:(-1,0) 5:(1,1) 6:(1,-1) 7:(-1,1) 8:(-1,-1)
__device__ const int c_oy[9] = {0, 0, 0, 1, -1, 1, 1, -1, -1};
__device__ const int c_ox[9] = {0, 1, -1, 0, 0, 1, -1, 1, -1};

// Stencil coefficients of M = I + A for node n, time t, batch b.
// Out-of-grid neighbor coefficients zeroed (matches VALID in reference).
__device__ __forceinline__ void stencil9(const float* __restrict__ kap,
                                         const float* __restrict__ m,
                                         const float* __restrict__ H,
                                         int b, int t, int n, float s[9]) {
    // Layouts: kappa (NB,1,NN,NT); m (NB,2,NN,NT); H (NB,2,2,NN,NT)
    float k   = kap[((size_t)b * NN + n) * NT + t];
    float mx  = m[(((size_t)b * 2 + 0) * NN + n) * NT + t];
    float my  = m[(((size_t)b * 2 + 1) * NN + n) * NT + t];
    float H11 = H[((((size_t)b * 2 + 0) * 2 + 0) * NN + n) * NT + t];
    float H01 = H[((((size_t)b * 2 + 0) * 2 + 1) * NN + n) * NT + t];
    float H10 = H[((((size_t)b * 2 + 1) * 2 + 0) * NN + n) * NT + t];
    float H22 = H[((((size_t)b * 2 + 1) * 2 + 1) * NN + n) * NT + t];
    float cc = 0.25f * (H01 + H10);                  // H12/(2 DX DY), DX=DY=1
    s[0] = 1.0f + k * k + 2.0f * H11 + 2.0f * H22;   // diag of M = 1 + c0
    s[1] =  0.5f * mx - H11;    // (0,+1)
    s[2] = -0.5f * mx - H11;    // (0,-1)
    s[3] =  0.5f * my - H22;    // (+1,0)
    s[4] = -0.5f * my - H22;    // (-1,0)
    s[5] = -cc;                 // (+1,+1)
    s[6] =  cc;                 // (+1,-1)
    s[7] =  cc;                 // (-1,+1)
    s[8] = -cc;                 // (-1,-1)
    int y = n >> 5, x = n & 31;
    if (x == NX - 1) { s[1] = 0.f; s[5] = 0.f; s[7] = 0.f; }
    if (x == 0)      { s[2] = 0.f; s[6] = 0.f; s[8] = 0.f; }
    if (y == NY - 1) { s[3] = 0.f; s[5] = 0.f; s[6] = 0.f; }
    if (y == 0)      { s[4] = 0.f; s[7] = 0.f; s[8] = 0.f; }
}

// One 64-thread wave per output row (b, g = t*NN + r). Q is pre-zeroed by
// hipMemsetAsync; this kernel writes ONLY the <=43 structurally-nonzero
// entries of the row:
//   diag block (t,t):       row r of MM[t] (+I for interior t), 5x5 stencil
//   column block (t-1):     -M[t-1][r, :]  (9 entries, t >= 1)
//   column block (t+1):     -M[t+1][r, :]  (9 entries, t <= NT-2)
__global__ __launch_bounds__(64) void spde_scatter(const float* __restrict__ kap,
                                                   const float* __restrict__ m,
                                                   const float* __restrict__ H,
                                                   float* __restrict__ Q) {
    const int oy[9] = {0, 0, 0, 1, -1, 1, 1, -1, -1};
    const int ox[9] = {0, 1, -1, 0, 0, 1, -1, 1, -1};

    int row = blockIdx.x;                 // 0 .. NB*NT*NN-1
    int b = row / (NT * NN);
    int g = row - b * (NT * NN);          // row within batch, 0..5119
    int t = g >> 10;
    int r = g & (NN - 1);
    int ry = r >> 5, rx = r & 31;
    int tid = threadIdx.x;

    // sk[d][(dy+1)*3+(dx+1)] : stencil of M[t] at neighbor node k_d of r
    // moff[z][e]             : -M[t-1][r, off e] (z=0) / -M[t+1][r, off e] (z=1)
    // accL[(dy+2)*5+(dx+2)]  : row r of MM[t] (+I if interior t)
    __shared__ float sk[9][9];
    __shared__ float moff[2][9];
    __shared__ float accL[25];

    if (tid < 9) {
        int ky = ry + c_oy[tid], kx = rx + c_ox[tid];
        bool valid = ((unsigned)ky < NY) && ((unsigned)kx < NX);
        int k = valid ? (ky * NX + kx) : r;   // clamp; invalid path killed by sr==0
        float s[9];
        stencil9(kap, m, H, b, t, k, s);
#pragma unroll
        for (int e = 0; e < 9; ++e)
            sk[tid][(oy[e] + 1) * 3 + (ox[e] + 1)] = s[e];
    } else if (tid == 9) {
        float s[9] = {0,0,0,0,0,0,0,0,0};
        if (t >= 1) stencil9(kap, m, H, b, t - 1, r, s);
#pragma unroll
        for (int e = 0; e < 9; ++e) moff[0][e] = -s[e];
    } else if (tid == 10) {
        float s[9] = {0,0,0,0,0,0,0,0,0};
        if (t <= NT - 2) stencil9(kap, m, H, b, t + 1, r, s);
#pragma unroll
        for (int e = 0; e < 9; ++e) moff[1][e] = -s[e];
    }
    __syncthreads();

    if (tid < 25) {
        int dy = tid / 5 - 2, dx = tid % 5 - 2;
        float a = 0.f;
#pragma unroll
        for (int d1 = 0; d1 < 9; ++d1) {
            int dy2 = dy - oy[d1], dx2 = dx - ox[d1];
            if (dy2 >= -1 && dy2 <= 1 && dx2 >= -1 && dx2 <= 1) {
                a += sk[0][(oy[d1] + 1) * 3 + (ox[d1] + 1)]
                   * sk[d1][(dy2 + 1) * 3 + (dx2 + 1)];
            }
        }
        if (tid == 12 && t >= 1 && t <= NT - 2) a += 1.0f;  // MM + I, interior t
        accL[tid] = a;
    }
    __syncthreads();

    size_t rowbase = ((size_t)b * QDIM + g) * QDIM;

    if (tid < 25) {
        // Diag block (t,t): entry (dy,dx) of the 5x5 tile
        int dy = tid / 5 - 2, dx = tid % 5 - 2;
        int cy = ry + dy, cx = rx + dx;
        if ((unsigned)cy < NY && (unsigned)cx < NX)
            Q[rowbase + (size_t)t * NN + cy * NX + cx] = accL[tid];
    } else if (tid >= 32 && tid < 41) {
        // Column block (t-1): -M[t-1][r, c]
        if (t >= 1) {
            int d = tid - 32;
            int cy = ry + c_oy[d], cx = rx + c_ox[d];
            if ((unsigned)cy < NY && (unsigned)cx < NX)
                Q[rowbase + (size_t)(t - 1) * NN + cy * NX + cx] = moff[0][d];
        }
    } else if (tid >= 48 && tid < 57) {
        // Column block (t+1): -M[t+1][r, c]
        if (t <= NT - 2) {
            int d = tid - 48;
            int cy = ry + c_oy[d], cx = rx + c_ox[d];
            if ((unsigned)cy < NY && (unsigned)cx < NX)
                Q[rowbase + (size_t)(t + 1) * NN + cy * NX + cx] = moff[1][d];
        }
    }
}

extern "C" void kernel_launch(void* const* d_in, const int* in_sizes, int n_in,
                              void* d_out, int out_size, void* d_ws, size_t ws_size,
                              hipStream_t stream) {
    const float* kap = (const float*)d_in[0];
    const float* m   = (const float*)d_in[1];
    const float* H   = (const float*)d_in[2];
    float* Q = (float*)d_out;

    // Zero the output via the runtime fill path (measured ~6.3 TB/s).
    hipMemsetAsync(d_out, 0, (size_t)out_size * sizeof(float), stream);

    // Then scatter only the nonzero entries, one wave per output row.
    int nrows = NB * NT * NN;  // 20480
    spde_scatter<<<nrows, 64, 0, stream>>>(kap, m, H, Q);
}

// Round 5
// 412.214 us; speedup vs baseline: 1.0580x; 1.0580x over previous
//
#include <hip/hip_runtime.h>

// Problem constants (from reference): N_T=5, 32x32 grid, N=1024, batch=4.
#define NT   5
#define NY   32
#define NX   32
#define NN   1024          // N = NY*NX
#define QDIM 5120          // NT * NN
#define NB   4

// Native clang vector type — required by __builtin_nontemporal_store
// (HIP's float4 is a class and is rejected).
typedef float vfloat4 __attribute__((ext_vector_type(4)));

// Canonical stencil offset order (matches reference's offs list):
// 0:(0,0) 1:(0,1) 2:(0,-1) 3:(1,0) 4:(-1,0) 5:(1,1) 6:(1,-1) 7:(-1,1) 8:(-1,-1)
__device__ const int c_oy[9] = {0, 0, 0, 1, -1, 1, 1, -1, -1};
__device__ const int c_ox[9] = {0, 1, -1, 0, 0, 1, -1, 1, -1};

// Stencil coefficients of M = I + A for node n, time t, batch b.
// Out-of-grid neighbor coefficients zeroed (matches VALID in reference).
__device__ __forceinline__ void stencil9(const float* __restrict__ kap,
                                         const float* __restrict__ m,
                                         const float* __restrict__ H,
                                         int b, int t, int n, float s[9]) {
    // Layouts: kappa (NB,1,NN,NT); m (NB,2,NN,NT); H (NB,2,2,NN,NT)
    float k   = kap[((size_t)b * NN + n) * NT + t];
    float mx  = m[(((size_t)b * 2 + 0) * NN + n) * NT + t];
    float my  = m[(((size_t)b * 2 + 1) * NN + n) * NT + t];
    float H11 = H[((((size_t)b * 2 + 0) * 2 + 0) * NN + n) * NT + t];
    float H01 = H[((((size_t)b * 2 + 0) * 2 + 1) * NN + n) * NT + t];
    float H10 = H[((((size_t)b * 2 + 1) * 2 + 0) * NN + n) * NT + t];
    float H22 = H[((((size_t)b * 2 + 1) * 2 + 1) * NN + n) * NT + t];
    float cc = 0.25f * (H01 + H10);                  // H12/(2 DX DY), DX=DY=1
    s[0] = 1.0f + k * k + 2.0f * H11 + 2.0f * H22;   // diag of M = 1 + c0
    s[1] =  0.5f * mx - H11;    // (0,+1)
    s[2] = -0.5f * mx - H11;    // (0,-1)
    s[3] =  0.5f * my - H22;    // (+1,0)
    s[4] = -0.5f * my - H22;    // (-1,0)
    s[5] = -cc;                 // (+1,+1)
    s[6] =  cc;                 // (+1,-1)
    s[7] =  cc;                 // (-1,+1)
    s[8] = -cc;                 // (-1,-1)
    int y = n >> 5, x = n & 31;
    if (x == NX - 1) { s[1] = 0.f; s[5] = 0.f; s[7] = 0.f; }
    if (x == 0)      { s[2] = 0.f; s[6] = 0.f; s[8] = 0.f; }
    if (y == NY - 1) { s[3] = 0.f; s[5] = 0.f; s[6] = 0.f; }
    if (y == 0)      { s[4] = 0.f; s[7] = 0.f; s[8] = 0.f; }
}

// One 256-thread block per output row (b, g = t*NN + r), single pass over Q.
// Phase 1: zero a 3-block LDS row image (blocks t-1, t, t+1) and compute the
//          11 needed stencils into LDS.
// Phase 2: scatter the <=43 nonzero values into the LDS row image.
// Phase 3: stream the 5120-column row to global: per unrolled block kk,
//          wave-uniform select (staged block vs zeros) -> float4 store.
// Every byte of Q is written exactly once; no memset pass.
__global__ __launch_bounds__(256) void spde_fused(const float* __restrict__ kap,
                                                  const float* __restrict__ m,
                                                  const float* __restrict__ H,
                                                  float* __restrict__ Q) {
    const int oy[9] = {0, 0, 0, 1, -1, 1, 1, -1, -1};
    const int ox[9] = {0, 1, -1, 0, 0, 1, -1, 1, -1};

    int row = blockIdx.x;                 // 0 .. NB*NT*NN-1
    int b = row / (NT * NN);
    int g = row - b * (NT * NN);          // row within batch, 0..5119
    int t = g >> 10;
    int r = g & (NN - 1);
    int ry = r >> 5, rx = r & 31;
    int tid = threadIdx.x;

    // lds_row[z][c]: row image for column-block t-1+z (z=0..2); unused z stay 0
    __shared__ float lds_row[3][NN];
    __shared__ float sk[9][9];     // stencil of M[t] at the 9 neighbors of r
    __shared__ float moff[2][9];   // -M[t-1][r,:] and -M[t+1][r,:]

    // ---- Phase 1: zero LDS row image; threads 0..10 compute stencils ----
    {
        vfloat4 z4 = {0.f, 0.f, 0.f, 0.f};
        vfloat4* p = (vfloat4*)&lds_row[0][0];     // 768 float4 slots
#pragma unroll
        for (int w = 0; w < 3; ++w) p[tid + 256 * w] = z4;
    }
    if (tid < 9) {
        int ky = ry + c_oy[tid], kx = rx + c_ox[tid];
        bool valid = ((unsigned)ky < NY) && ((unsigned)kx < NX);
        int k = valid ? (ky * NX + kx) : r;   // clamp; invalid path killed by sr==0
        float s[9];
        stencil9(kap, m, H, b, t, k, s);
#pragma unroll
        for (int e = 0; e < 9; ++e)
            sk[tid][(oy[e] + 1) * 3 + (ox[e] + 1)] = s[e];
    } else if (tid == 9) {
        float s[9] = {0,0,0,0,0,0,0,0,0};
        if (t >= 1) stencil9(kap, m, H, b, t - 1, r, s);
#pragma unroll
        for (int e = 0; e < 9; ++e) moff[0][e] = -s[e];
    } else if (tid == 10) {
        float s[9] = {0,0,0,0,0,0,0,0,0};
        if (t <= NT - 2) stencil9(kap, m, H, b, t + 1, r, s);
#pragma unroll
        for (int e = 0; e < 9; ++e) moff[1][e] = -s[e];
    }
    __syncthreads();

    // ---- Phase 2: scatter nonzeros into the LDS row image ----
    if (tid < 25) {
        // Diag block (z=1): entry (dy,dx) of row r of MM[t] (+I interior)
        int dy = tid / 5 - 2, dx = tid % 5 - 2;
        float a = 0.f;
#pragma unroll
        for (int d1 = 0; d1 < 9; ++d1) {
            int dy2 = dy - oy[d1], dx2 = dx - ox[d1];
            if (dy2 >= -1 && dy2 <= 1 && dx2 >= -1 && dx2 <= 1) {
                a += sk[0][(oy[d1] + 1) * 3 + (ox[d1] + 1)]
                   * sk[d1][(dy2 + 1) * 3 + (dx2 + 1)];
            }
        }
        if (tid == 12 && t >= 1 && t <= NT - 2) a += 1.0f;  // MM + I, interior t
        int cy = ry + dy, cx = rx + dx;
        if ((unsigned)cy < NY && (unsigned)cx < NX)
            lds_row[1][cy * NX + cx] = a;
    } else if (tid >= 32 && tid < 41) {
        // Block t-1 (z=0): -M[t-1][r, c]
        if (t >= 1) {
            int d = tid - 32;
            int cy = ry + c_oy[d], cx = rx + c_ox[d];
            if ((unsigned)cy < NY && (unsigned)cx < NX)
                lds_row[0][cy * NX + cx] = moff[0][d];
        }
    } else if (tid >= 48 && tid < 57) {
        // Block t+1 (z=2): -M[t+1][r, c]
        if (t <= NT - 2) {
            int d = tid - 48;
            int cy = ry + c_oy[d], cx = rx + c_ox[d];
            if ((unsigned)cy < NY && (unsigned)cx < NX)
                lds_row[2][cy * NX + cx] = moff[1][d];
        }
    }
    __syncthreads();

    // ---- Phase 3: stream the full row, one 1024-col block per iteration ----
    // Thread tid covers columns [4*tid, 4*tid+3] of each block; block kk's
    // staged image index z = kk - t + 1 is wave-uniform.
    float* dst = Q + ((size_t)b * QDIM + g) * QDIM + 4 * tid;
    const vfloat4* src = (const vfloat4*)&lds_row[0][4 * tid];
    vfloat4 z4 = {0.f, 0.f, 0.f, 0.f};
#pragma unroll
    for (int kk = 0; kk < NT; ++kk) {
        int z = kk - t + 1;
        vfloat4 v = ((unsigned)z < 3u) ? src[(size_t)z * (NN / 4)] : z4;
        __builtin_nontemporal_store(v, (vfloat4*)(dst + (size_t)kk * NN));
    }
}

extern "C" void kernel_launch(void* const* d_in, const int* in_sizes, int n_in,
                              void* d_out, int out_size, void* d_ws, size_t ws_size,
                              hipStream_t stream) {
    const float* kap = (const float*)d_in[0];
    const float* m   = (const float*)d_in[1];
    const float* H   = (const float*)d_in[2];
    float* Q = (float*)d_out;

    int nrows = NB * NT * NN;  // 20480 blocks, one per output row
    spde_fused<<<nrows, 256, 0, stream>>>(kap, m, H, Q);
}